// Round 1
// baseline (276.636 us; speedup 1.0000x reference)
//
#include <hip/hip_runtime.h>
#include <hip/hip_bf16.h>
#include <cstddef>

// ---------------- problem constants ----------------
#define BB   8
#define HH   120
#define WW   160
#define HW   19200          // HH*WW
#define NPIX 153600         // BB*HW
#define CORC 196

#define AS_  ((float)(6.0/127.0))   // ACT_SCALE, matches f64-then-cast like jax
#define FS_  0.03125f               // FLOW_SCALE = 3.96875/127 = 2^-5 exactly

// ws float-offsets
#define OFF_WC1 16                  // [196][96] dequant fp32 (transposed)
#define OFF_WF1 18832               // [64][2]  dequant fp32
#define OFF_WF2 18960               // [64][32] dequant fp32 (transposed)
#define OFF_WD  21008               // [128][9] integer-valued fp32
#define OFF_WP  22160               // [128][80] integer-valued fp32 (transposed)
#define CFQ_BYTE_OFF 131072         // int8 activation buffer, 8*128*19200 bytes

__device__ __forceinline__ float clip127(float x) {
    return fminf(fmaxf(x, -127.f), 127.f);
}

// ---------------- kernel 0: weight fake-quant ----------------
__global__ __launch_bounds__(256) void quant_weights(
    const float* __restrict__ Wc1, const float* __restrict__ Wf1,
    const float* __restrict__ Wf2, const float* __restrict__ Wd,
    const float* __restrict__ Wp,  float* __restrict__ ws)
{
    __shared__ float red[256];
    const int t = blockIdx.x;
    const float* src = (t == 0) ? Wc1 : (t == 1) ? Wf1 : (t == 2) ? Wf2 : (t == 3) ? Wd : Wp;
    const int n = (t == 0) ? 18816 : (t == 1) ? 128 : (t == 2) ? 2048 : (t == 3) ? 1152 : 10240;
    const int tid = threadIdx.x;

    float m = 0.f;
    for (int i = tid; i < n; i += 256) m = fmaxf(m, fabsf(src[i]));
    red[tid] = m;
    __syncthreads();
    for (int s = 128; s > 0; s >>= 1) {
        if (tid < s) red[tid] = fmaxf(red[tid], red[tid + s]);
        __syncthreads();
    }
    const float s = red[0] / 127.0f + 1e-12f;

    for (int i = tid; i < n; i += 256) {
        const float q = clip127(rintf(src[i] / s));
        if (t == 0) {            // Wc1 [96][196] -> transposed dequant [196][96]
            int o = i / 196, c = i % 196;
            ws[OFF_WC1 + c * 96 + o] = s * q;
        } else if (t == 1) {     // Wf1 [64][2]
            ws[OFF_WF1 + i] = s * q;
        } else if (t == 2) {     // Wf2 [32][64] -> transposed [64][32]
            int o = i / 64, c = i % 64;
            ws[OFF_WF2 + c * 32 + o] = s * q;
        } else if (t == 3) {     // Wd [128][9]: keep integer q
            ws[OFF_WD + i] = q;
        } else {                 // Wp [80][128] -> transposed integer q [128][80]
            int o = i / 128, c = i % 128;
            ws[OFF_WP + c * 80 + o] = q;
        }
    }
    if (tid == 0) {
        if (t == 3) ws[0] = s;   // depthwise scale
        if (t == 4) ws[1] = s;   // pointwise scale
    }
}

// ---------------- kernel 1: convc1 + convf1/f2 + QuantCat + ACT requant ----------------
// one thread per pixel; writes int8 q-values (x = AS_*q) for all 128 channels
__global__ __launch_bounds__(256) void k1_mlp(
    const float* __restrict__ flow, const float* __restrict__ corr,
    const float* __restrict__ bc1,  const float* __restrict__ bf1,
    const float* __restrict__ bf2,  const float* __restrict__ ws,
    signed char* __restrict__ cfq)
{
    const int p  = blockIdx.x * 256 + threadIdx.x;
    const int b  = p / HW;
    const int hw = p % HW;

    // ---- convc1: 196 -> 96 ----
    const float* cp = corr + (size_t)b * CORC * HW + hw;
    const float* wc = ws + OFF_WC1;
    float acc[96];
#pragma unroll
    for (int o = 0; o < 96; ++o) acc[o] = 0.f;
    for (int c = 0; c < CORC; ++c) {
        const float a = cp[(size_t)c * HW];
        const float* w = wc + c * 96;   // uniform address -> scalar loads
#pragma unroll
        for (int o = 0; o < 96; ++o) acc[o] = fmaf(a, w[o], acc[o]);
    }

    signed char* op = cfq + (size_t)b * 128 * HW + hw;
#pragma unroll
    for (int o = 0; o < 96; ++o) {
        float v  = acc[o] + bc1[o];
        float aq = AS_ * clip127(rintf(v / AS_));   // act_quant(., ACT)
        float r  = fmaxf(aq, 0.f);                  // relu
        float k  = fminf(rintf(r * 32.f), 127.f);   // act_quant(., FLOW): /FS == *32 exact
        float cf = k * FS_;                         // exact (FS = 2^-5); outer cat-quant is identity
        float q8 = clip127(rintf(cf / AS_));        // act_quant(cf, ACT) -> int code
        op[(size_t)o * HW] = (signed char)(int)q8;
    }

    // ---- convf1: 2 -> 64 (relu, no out-quant) then input ACT quant ----
    const float f0 = flow[(size_t)(b * 2) * HW + hw];
    const float f1 = flow[(size_t)(b * 2 + 1) * HW + hw];
    float af[64];
#pragma unroll
    for (int o = 0; o < 64; ++o) {
        float v  = f0 * ws[OFF_WF1 + 2 * o] + f1 * ws[OFF_WF1 + 2 * o + 1] + bf1[o];
        float r  = fmaxf(v, 0.f);
        float qf = fminf(rintf(r / AS_), 127.f);    // r >= 0
        af[o] = AS_ * qf;                            // dequantized activation (matches ref value)
    }

    // ---- convf2: 64 -> 32 ----
    float a2[32];
#pragma unroll
    for (int o = 0; o < 32; ++o) a2[o] = 0.f;
    for (int c = 0; c < 64; ++c) {
        const float a = af[c];
        const float* w = ws + OFF_WF2 + c * 32;
#pragma unroll
        for (int o = 0; o < 32; ++o) a2[o] = fmaf(a, w[o], a2[o]);
    }
#pragma unroll
    for (int o = 0; o < 32; ++o) {
        float v  = a2[o] + bf2[o];
        float aq = AS_ * clip127(rintf(v / AS_));
        float r  = fmaxf(aq, 0.f);
        float k  = fminf(rintf(r * 32.f), 127.f);
        float cf = k * FS_;
        float q8 = clip127(rintf(cf / AS_));
        op[(size_t)(96 + o) * HW] = (signed char)(int)q8;
    }
}

// ---------------- kernel 2: depthwise 3x3 + pointwise + final quant-cat ----------------
// 8x32 pixel tile per block; int8 tile+halo staged in LDS
__global__ __launch_bounds__(256) void k2_dwpw(
    const float* __restrict__ flow, const float* __restrict__ bd,
    const float* __restrict__ bp,   const float* __restrict__ ws,
    const signed char* __restrict__ cfq, float* __restrict__ out)
{
    __shared__ unsigned int lds[12800];   // 10 rows * 128 ch * 40 bytes
    const int bid = blockIdx.x;
    const int b  = bid / 75;
    const int rem = bid % 75;
    const int h0 = (rem / 5) * 8;
    const int w0 = (rem % 5) * 32;

    // stage tile+halo: rows h0-1..h0+8, bytes w0-4..w0+35 (dword aligned, fully in/out)
    for (int j = threadIdx.x; j < 12800; j += 256) {
        const int i   = j % 10;
        const int c   = (j / 10) % 128;
        const int row = j / 1280;
        const int h   = h0 - 1 + row;
        const int wb  = w0 - 4 + 4 * i;
        unsigned int v = 0u;
        if (h >= 0 && h < HH && wb >= 0 && wb <= WW - 4)
            v = *(const unsigned int*)(cfq + ((size_t)(b * 128 + c) * HW + (size_t)h * WW + wb));
        lds[(row * 128 + c) * 10 + i] = v;
    }
    __syncthreads();

    const int tx = threadIdx.x % 32;
    const int ty = threadIdx.x / 32;
    const signed char* lds8 = (const signed char*)lds;

    const float sd   = ws[0];
    const float sp   = ws[1];
    const float ASsd = AS_ * sd;
    const float ASsp = AS_ * sp;

    float accp[80];
#pragma unroll
    for (int o = 0; o < 80; ++o) accp[o] = 0.f;

    for (int c = 0; c < 128; ++c) {
        // depthwise 3x3, exact integer sum
        float s = 0.f;
#pragma unroll
        for (int dy = 0; dy < 3; ++dy) {
            const int base = ((ty + dy) * 128 + c) * 40 + tx + 3;
#pragma unroll
            for (int dd = 0; dd < 3; ++dd) {
                const float a = (float)lds8[base + dd];
                s = fmaf(a, ws[OFF_WD + c * 9 + dy * 3 + dd], s);
            }
        }
        const float d  = fmaf(ASsd, s, bd[c]);
        const float q2 = clip127(rintf(d / AS_));     // act_quant(d, ACT) int code
        const float* w = ws + OFF_WP + c * 80;        // uniform -> scalar loads
#pragma unroll
        for (int o = 0; o < 80; ++o) accp[o] = fmaf(q2, w[o], accp[o]);
    }

    const int h  = h0 + ty;
    const int w  = w0 + tx;
    const int hw = h * WW + w;
    float* opx = out + (size_t)b * 82 * HW + hw;
#pragma unroll
    for (int o = 0; o < 80; ++o) {
        float v = fmaf(ASsp, accp[o], bp[o]);
        float r = fmaxf(v, 0.f);                      // relu
        float k = fminf(rintf(r * 32.f), 127.f);      // FLOW quant (outer cat-quant = identity)
        opx[(size_t)o * HW] = k * FS_;
    }
    // channels 80..81: act_quant(flow, FLOW) (outer quant identity)
#pragma unroll
    for (int j = 0; j < 2; ++j) {
        float f = flow[(size_t)(b * 2 + j) * HW + hw];
        float k = clip127(rintf(f * 32.f));
        opx[(size_t)(80 + j) * HW] = k * FS_;
    }
}

// ---------------- launcher ----------------
extern "C" void kernel_launch(void* const* d_in, const int* in_sizes, int n_in,
                              void* d_out, int out_size, void* d_ws, size_t ws_size,
                              hipStream_t stream) {
    const float* flow = (const float*)d_in[0];
    const float* corr = (const float*)d_in[1];
    const float* Wc1  = (const float*)d_in[2];
    const float* bc1  = (const float*)d_in[3];
    const float* Wf1  = (const float*)d_in[4];
    const float* bf1  = (const float*)d_in[5];
    const float* Wf2  = (const float*)d_in[6];
    const float* bf2  = (const float*)d_in[7];
    const float* Wd   = (const float*)d_in[8];
    const float* bd   = (const float*)d_in[9];
    const float* Wp   = (const float*)d_in[10];
    const float* bp   = (const float*)d_in[11];

    float* ws = (float*)d_ws;
    signed char* cfq = (signed char*)d_ws + CFQ_BYTE_OFF;
    float* out = (float*)d_out;

    quant_weights<<<5, 256, 0, stream>>>(Wc1, Wf1, Wf2, Wd, Wp, ws);
    k1_mlp<<<NPIX / 256, 256, 0, stream>>>(flow, corr, bc1, bf1, bf2, ws, cfq);
    k2_dwpw<<<600, 256, 0, stream>>>(flow, bd, bp, ws, cfq, out);
}